// Round 4
// baseline (437.771 us; speedup 1.0000x reference)
//
#include <hip/hip_runtime.h>

typedef __bf16 bf16;
typedef __bf16 bf16x8 __attribute__((ext_vector_type(8)));
typedef float f32x4 __attribute__((ext_vector_type(4)));
typedef float f32x16 __attribute__((ext_vector_type(16)));
typedef unsigned int uint;
typedef unsigned short ushort;

typedef const __attribute__((address_space(1))) void* gas_ptr;
typedef __attribute__((address_space(3))) void* las_ptr;

__device__ __forceinline__ void load16_lds(const void* g, void* l) {
  __builtin_amdgcn_global_load_lds((gas_ptr)g, (las_ptr)l, 16, 0, 0);
}

__device__ __forceinline__ uint pkbf(float a, float b) {
  ushort ua = __builtin_bit_cast(ushort, (bf16)a);
  ushort ub = __builtin_bit_cast(ushort, (bf16)b);
  return (uint)ua | ((uint)ub << 16);
}

// ---------------------------------------------------------------------------
// x fp32 -> bf16 cast
// ---------------------------------------------------------------------------
__global__ __launch_bounds__(256) void cast_f32_bf16(
    const float* __restrict__ in, bf16* __restrict__ out) {
  size_t i = (size_t)blockIdx.x * 256 + threadIdx.x;
  const float4* p = reinterpret_cast<const float4*>(in) + i * 2;
  float4 a = p[0], b = p[1];
  bf16x8 v;
  v[0] = (bf16)a.x; v[1] = (bf16)a.y; v[2] = (bf16)a.z; v[3] = (bf16)a.w;
  v[4] = (bf16)b.x; v[5] = (bf16)b.y; v[6] = (bf16)b.z; v[7] = (bf16)b.w;
  reinterpret_cast<bf16x8*>(out)[i] = v;
}

// ---------------------------------------------------------------------------
// Weight transpose + cast: in [K][N] fp32 -> out [N][K] bf16
// ---------------------------------------------------------------------------
__global__ __launch_bounds__(256) void transpose_f32_bf16(
    const float* __restrict__ in, bf16* __restrict__ out, int K, int N) {
  __shared__ __attribute__((aligned(16))) bf16 tile[64 * 72];
  const int k0 = blockIdx.y * 64, n0 = blockIdx.x * 64;
  const int tid = threadIdx.x;
  for (int c = tid; c < 1024; c += 256) {
    int ki = c >> 4, j4 = c & 15;
    float4 f = *reinterpret_cast<const float4*>(in + (size_t)(k0 + ki) * N + n0 + j4 * 4);
    bf16* t = &tile[ki * 72 + j4 * 4];
    t[0] = (bf16)f.x; t[1] = (bf16)f.y; t[2] = (bf16)f.z; t[3] = (bf16)f.w;
  }
  __syncthreads();
  for (int c = tid; c < 512; c += 256) {
    int ni = c >> 3, k8 = c & 7;
    bf16x8 v;
    for (int j = 0; j < 8; j++) v[j] = tile[(k8 * 8 + j) * 72 + ni];
    *reinterpret_cast<bf16x8*>(out + (size_t)(n0 + ni) * K + k0 + k8 * 8) = v;
  }
}

// ---------------------------------------------------------------------------
// GEMM (unchanged from R3): C[M,N] = A * Bt^T, 128x128 tile, global_load_lds
// ---------------------------------------------------------------------------
template <typename CT>
__global__ __launch_bounds__(256, 2) void gemm_lds(
    const bf16* __restrict__ A, const bf16* __restrict__ Bt,
    CT* __restrict__ C, int M, int N, int K) {
  __shared__ __attribute__((aligned(16))) bf16 As[128 * 64];
  __shared__ __attribute__((aligned(16))) bf16 Bs[128 * 64];
  const int tid = threadIdx.x;
  const int wave = tid >> 6;
  const int lane = tid & 63;
  const int l15 = lane & 15;
  const int quad = lane >> 4;
  const int m0 = blockIdx.y * 128;
  const int n0 = blockIdx.x * 128;
  const int wm = (wave >> 1) * 64;
  const int wn = (wave & 1) * 64;

  f32x4 acc[4][4] = {};

  for (int kt = 0; kt < K; kt += 64) {
    __syncthreads();
    for (int it = 0; it < 4; ++it) {
      int p = it * 256 + wave * 64 + lane;
      int row = p >> 3, kc = (p & 7) ^ (row & 7);
      load16_lds(A + (size_t)(m0 + row) * K + kt + kc * 8, &As[p * 8]);
      load16_lds(Bt + (size_t)(n0 + row) * K + kt + kc * 8, &Bs[p * 8]);
    }
    __syncthreads();
    for (int kk = 0; kk < 64; kk += 32) {
      const int kc = (kk >> 3) + quad;
      bf16x8 af[4], bfr[4];
      for (int i = 0; i < 4; i++) {
        int row = wm + i * 16 + l15;
        af[i] = *reinterpret_cast<const bf16x8*>(&As[(row * 8 + (kc ^ (row & 7))) * 8]);
      }
      for (int j = 0; j < 4; j++) {
        int row = wn + j * 16 + l15;
        bfr[j] = *reinterpret_cast<const bf16x8*>(&Bs[(row * 8 + (kc ^ (row & 7))) * 8]);
      }
      for (int i = 0; i < 4; i++)
        for (int j = 0; j < 4; j++)
          acc[i][j] = __builtin_amdgcn_mfma_f32_16x16x32_bf16(af[i], bfr[j], acc[i][j], 0, 0, 0);
    }
  }

  for (int i = 0; i < 4; i++)
    for (int j = 0; j < 4; j++)
      for (int r = 0; r < 4; r++) {
        int row = m0 + wm + i * 16 + quad * 4 + r;
        int col = n0 + wn + j * 16 + l15;
        C[(size_t)row * N + col] = (CT)acc[i][j][r];
      }
}

// ---------------------------------------------------------------------------
// Flash attention v3: 32x32x16 MFMA, 64 q/wave, TK=128, no max-subtraction.
// qkv: [B*T, 3072] bf16. Grid (B*H=64, T/256=8), block 256 = 4 waves.
// S^T = K·Q^T (A=K-frag, B=Q-frag); O^T = V^T·P^T (A=V^T-frag, B=P^T-frag).
// Ks: chunk-XOR-swizzled [key128][d64] for global_load_lds.
// Vst: [d64][keypair dword 64], XOR-swizzled (conflict-free).
// Pb: per-wave [q64][key32] bf16, XOR-swizzled (min-cycle banks).
// ---------------------------------------------------------------------------
__device__ __forceinline__ int edz(int d) { return ((d >> 3) ^ d) & 7; }

__global__ __launch_bounds__(256, 2) void attn_kernel(
    const bf16* __restrict__ qkv, bf16* __restrict__ out) {
  __shared__ __attribute__((aligned(16))) bf16 Ks[128 * 64];
  __shared__ __attribute__((aligned(16))) uint Vst[64 * 64];
  __shared__ __attribute__((aligned(16))) uint Pb[4][64 * 16];

  const int tid = threadIdx.x;
  const int wave = tid >> 6;
  const int lane = tid & 63;
  const int lh = lane >> 5;   // half of wave
  const int q5 = lane & 31;   // 0..31
  const int b = blockIdx.x >> 4;
  const int h = blockIdx.x & 15;
  const int qt0 = blockIdx.y * 256;
  const bf16* base = qkv + (size_t)b * 2048 * 3072 + h * 64;
  uint* PbW = &Pb[wave][0];
  const float L2E = 1.44269504f;

  // Q fragments: qreg[qblk][dc] = Q[q][dc*16 + lh*8 .. +7], pre-scaled by log2e
  bf16x8 qreg[2][4];
#pragma unroll
  for (int qblk = 0; qblk < 2; qblk++) {
    const bf16* qrow = base + (size_t)(qt0 + wave * 64 + qblk * 32 + q5) * 3072;
#pragma unroll
    for (int dc = 0; dc < 4; dc++) {
      bf16x8 v = *reinterpret_cast<const bf16x8*>(qrow + dc * 16 + lh * 8);
#pragma unroll
      for (int j = 0; j < 8; j++) v[j] = (bf16)((float)v[j] * L2E);
      qreg[qblk][dc] = v;
    }
  }

  f32x16 o[2][2] = {};  // [dblk][qblk], O^T C-layout
  float l_part[2] = {0.f, 0.f};

  for (int kt = 0; kt < 2048; kt += 128) {
    __syncthreads();
    // K: global_load_lds, chunk-swizzled (slot p: key=p>>3, kc=(p&7)^(key&7))
#pragma unroll
    for (int it = 0; it < 4; ++it) {
      int p = it * 256 + tid;
      int key = p >> 3, kc = (p & 7) ^ (key & 7);
      load16_lds(base + (size_t)(kt + key) * 3072 + 1024 + kc * 8, &Ks[p * 8]);
    }
    // V: transpose via dword-pair packing into swizzled [d][kdw]
#pragma unroll
    for (int half = 0; half < 2; half++) {
      int kd = half * 32 + (tid >> 3);
      int oct = tid & 7;
      const bf16* vr = base + (size_t)(kt + kd * 2) * 3072 + 2048 + oct * 8;
      bf16x8 r0 = *reinterpret_cast<const bf16x8*>(vr);
      bf16x8 r1 = *reinterpret_cast<const bf16x8*>(vr + 3072);
      const ushort* u0 = reinterpret_cast<const ushort*>(&r0);
      const ushort* u1 = reinterpret_cast<const ushort*>(&r1);
#pragma unroll
      for (int i = 0; i < 8; i++) {
        int d = oct * 8 + i;
        Vst[d * 64 + (kd ^ (edz(d) * 4))] = (uint)u0[i] | ((uint)u1[i] << 16);
      }
    }
    __syncthreads();

#pragma unroll
    for (int kblk = 0; kblk < 4; kblk++) {
      // K A-fragments for this 32-key block
      bf16x8 ak[4];
#pragma unroll
      for (int dc = 0; dc < 4; dc++) {
        int key = kblk * 32 + q5;
        int slot = key * 8 + ((dc * 2 + lh) ^ (key & 7));
        ak[dc] = *reinterpret_cast<const bf16x8*>(&Ks[slot * 8]);
      }
      // S^T blocks + exp + pack + store P
#pragma unroll
      for (int qblk = 0; qblk < 2; qblk++) {
        f32x16 s = {};
#pragma unroll
        for (int dc = 0; dc < 4; dc++)
          s = __builtin_amdgcn_mfma_f32_32x32x16_bf16(ak[dc], qreg[qblk][dc], s, 0, 0, 0);
        float psum = 0.f;
#pragma unroll
        for (int t = 0; t < 4; t++) {
          float p0 = __builtin_amdgcn_exp2f(s[4 * t + 0]);
          float p1 = __builtin_amdgcn_exp2f(s[4 * t + 1]);
          float p2 = __builtin_amdgcn_exp2f(s[4 * t + 2]);
          float p3 = __builtin_amdgcn_exp2f(s[4 * t + 3]);
          psum += (p0 + p1) + (p2 + p3);
          uint d0 = pkbf(p0, p1), d1 = pkbf(p2, p3);
          uint dwa = (qblk * 32 + q5) * 16 + ((4 * t) ^ ((q5 & 3) * 4)) + 2 * lh;
          uint2 st = {d0, d1};
          *reinterpret_cast<uint2*>(&PbW[dwa]) = st;
        }
        l_part[qblk] += psum;
      }
      // P^T B-fragments (wave-private LDS round trip)
      bf16x8 bp[2][2];
#pragma unroll
      for (int qblk = 0; qblk < 2; qblk++)
#pragma unroll
        for (int cl = 0; cl < 2; cl++) {
          int t_r = 2 * cl + lh;
          uint dwa = (qblk * 32 + q5) * 16 + ((4 * t_r) ^ ((q5 & 3) * 4));
          uint4 u = *reinterpret_cast<const uint4*>(&PbW[dwa]);
          bp[qblk][cl] = __builtin_bit_cast(bf16x8, u);
        }
      // O^T += V^T · P^T
#pragma unroll
      for (int dblk = 0; dblk < 2; dblk++)
#pragma unroll
        for (int cl = 0; cl < 2; cl++) {
          int d = dblk * 32 + q5;
          int c = kblk * 2 + cl;
          uint4 uv = *reinterpret_cast<const uint4*>(&Vst[d * 64 + ((c * 8 + lh * 4) ^ (edz(d) * 4))]);
          bf16x8 av = __builtin_bit_cast(bf16x8, uv);
#pragma unroll
          for (int qblk = 0; qblk < 2; qblk++)
            o[dblk][qblk] = __builtin_amdgcn_mfma_f32_32x32x16_bf16(av, bp[qblk][cl], o[dblk][qblk], 0, 0, 0);
        }
    }
  }

  // finalize: l = own + partner-half, normalize, write O (row q, cols d)
#pragma unroll
  for (int qblk = 0; qblk < 2; qblk++) {
    float l = l_part[qblk] + __shfl_xor(l_part[qblk], 32, 64);
    float inv = 1.0f / l;
    bf16* orow = out + (size_t)(b * 2048 + qt0 + wave * 64 + qblk * 32 + q5) * 1024 + h * 64;
#pragma unroll
    for (int dblk = 0; dblk < 2; dblk++)
#pragma unroll
      for (int g4 = 0; g4 < 4; g4++) {
        uint d0 = pkbf(o[dblk][qblk][4 * g4 + 0] * inv, o[dblk][qblk][4 * g4 + 1] * inv);
        uint d1 = pkbf(o[dblk][qblk][4 * g4 + 2] * inv, o[dblk][qblk][4 * g4 + 3] * inv);
        uint2 st = {d0, d1};
        *reinterpret_cast<uint2*>(orow + dblk * 32 + g4 * 8 + lh * 4) = st;
      }
  }
}

// ---------------------------------------------------------------------------
// Launch
// ---------------------------------------------------------------------------
extern "C" void kernel_launch(void* const* d_in, const int* in_sizes, int n_in,
                              void* d_out, int out_size, void* d_ws, size_t ws_size,
                              hipStream_t stream) {
  const float* x = (const float*)d_in[0];       // [8192, 1024] fp32
  const float* w_qkv = (const float*)d_in[1];   // [1024, 3072] fp32
  const float* w_proj = (const float*)d_in[2];  // [1024, 1024] fp32
  float* out = (float*)d_out;                   // [8192, 1024] fp32

  bf16* ws = (bf16*)d_ws;
  bf16* x_bf = ws;                              // [8192,1024]
  bf16* wqkvT = x_bf + (size_t)8192 * 1024;     // [3072,1024]
  bf16* wprojT = wqkvT + 3072 * 1024;           // [1024,1024]
  bf16* qkv = wprojT + 1024 * 1024;             // [8192,3072]
  bf16* attn_out = qkv + (size_t)8192 * 3072;   // [8192,1024]

  cast_f32_bf16<<<4096, 256, 0, stream>>>(x, x_bf);
  transpose_f32_bf16<<<dim3(48, 16), 256, 0, stream>>>(w_qkv, wqkvT, 1024, 3072);
  transpose_f32_bf16<<<dim3(16, 16), 256, 0, stream>>>(w_proj, wprojT, 1024, 1024);
  gemm_lds<bf16><<<dim3(24, 64), 256, 0, stream>>>(x_bf, wqkvT, qkv, 8192, 3072, 1024);
  attn_kernel<<<dim3(64, 8), 256, 0, stream>>>(qkv, attn_out);
  gemm_lds<float><<<dim3(8, 64), 256, 0, stream>>>(attn_out, wprojT, out, 8192, 1024, 1024);
}